// Round 9
// baseline (244.664 us; speedup 1.0000x reference)
//
#include <hip/hip_runtime.h>
#include <hip/hip_bf16.h>

// Shapes (fixed by the reference)
#define L_DIM 4
#define N_DIM 2048
#define DIN   1024
#define H_DIM 8
#define DH    64
#define INNER 512   // H*DH

typedef __attribute__((ext_vector_type(8))) short short8;
typedef __attribute__((ext_vector_type(4))) float f32x4;

__device__ __forceinline__ unsigned short f2bf(float f) {
  unsigned u = __builtin_bit_cast(unsigned, f);
  u += 0x7fffu + ((u >> 16) & 1u);   // RNE
  return (unsigned short)(u >> 16);
}

// single-instruction 2xf32 -> packed bf16x2 (RNE); low16 = a, high16 = b
__device__ __forceinline__ unsigned cvtpk(float a, float b) {
  unsigned r;
  asm("v_cvt_pk_bf16_f32 %0, %1, %2" : "=v"(r) : "v"(a), "v"(b));
  return r;
}

// v_exp_f32 computes 2^x; log2e pre-folded into the softmax scale.
__device__ __forceinline__ float fexp2(float x) {
  float r;
  asm("v_exp_f32 %0, %1" : "=v"(r) : "v"(x));
  return r;
}

// async global->LDS, 16B per lane; lds base must be wave-uniform
typedef __attribute__((address_space(3))) unsigned int lds_uint;
typedef const __attribute__((address_space(1))) unsigned int glob_uint;
__device__ __forceinline__ void gl_lds16(const unsigned short* g,
                                         unsigned short* l) {
  __builtin_amdgcn_global_load_lds((glob_uint*)g, (lds_uint*)l, 16, 0, 0);
}

// ------------------------------------------------- fused casts + mask bias
__global__ void cast_all(const float* __restrict__ x,
                         const float* __restrict__ wq,
                         const float* __restrict__ wk,
                         const float* __restrict__ wv,
                         const float* __restrict__ wo,
                         unsigned short* __restrict__ xb,
                         unsigned short* __restrict__ w3,
                         unsigned short* __restrict__ wob,
                         const unsigned char* __restrict__ mraw,
                         float* __restrict__ bias) {
  __shared__ int votes[2];
  int bid = blockIdx.x, t = threadIdx.x;
  if (bid == 10240) {
    // mask -> additive bias (0 valid, -1e30 masked); dtype sniffed.
    if (t < 2) votes[t] = 0;
    __syncthreads();
    const unsigned int* m32 = (const unsigned int*)mraw;
    int anyf = 0, any8 = 0;
    for (int i = t; i < 2048; i += 256) {
      unsigned w = m32[i];
      if (w == 0x3f800000u) anyf = 1;
      if (w & 0xffffff00u) any8 = 1;
    }
    if (anyf) atomicOr(&votes[0], 1);
    if (any8) atomicOr(&votes[1], 1);
    __syncthreads();
    int fmt = votes[0] ? 2 : (votes[1] ? 1 : 0);
    for (int i = t; i < L_DIM * N_DIM; i += 256) {
      int mv;
      if (fmt == 2)      mv = ((const float*)mraw)[i] != 0.0f;
      else if (fmt == 1) mv = mraw[i] != 0;
      else               mv = ((const int*)mraw)[i] != 0;
      bias[i] = mv ? 0.0f : -1e30f;
    }
    return;
  }
  int i = (bid * 256 + t) * 4;
  const float* src; unsigned short* dst; int off;
  if (i < 8388608)      { src = x;  dst = xb;           off = i; }
  else if (i < 8912896) { src = wq; dst = w3;           off = i - 8388608; }
  else if (i < 9437184) { src = wk; dst = w3 + 524288;  off = i - 8912896; }
  else if (i < 9961472) { src = wv; dst = w3 + 1048576; off = i - 9437184; }
  else                  { src = wo; dst = wob;          off = i - 9961472; }
  float4 f = *(const float4*)(src + off);
  ushort4 o4;
  o4.x = f2bf(f.x); o4.y = f2bf(f.y); o4.z = f2bf(f.z); o4.w = f2bf(f.w);
  *(ushort4*)(dst + off) = o4;
}

// ---------------------------------------------------------------- QKV GEMM
// C[8192][1536] = Xb[8192][1024] @ W3^T. r13 structure: 512 threads /
// 8 waves, 128x128/BK=32 dbuf-one-barrier, LDS 32KB, 3 blocks/CU.
// r14: this kernel is LAUNCHED TWICE as a duration bisection probe (second
// launch rewrites identical outputs; deterministic, graph-safe). The total
// delta vs the single-launch baseline measures qkv's warm duration, which
// three rounds of neutral restructures could not pin down.
__launch_bounds__(512, 6)
__global__ void gemm_qkv(const unsigned short* __restrict__ xb,
                         const unsigned short* __restrict__ w3,
                         unsigned short* __restrict__ qp,
                         unsigned short* __restrict__ kp,
                         unsigned short* __restrict__ vtp) {
  __shared__ __align__(16) unsigned short Sh[16384];  // A dbuf | B dbuf
  const int tid = threadIdx.x, lane = tid & 63, wid = tid >> 6;  // 0..7
  const int l16 = lane & 15, quad = lane >> 4;
  const int wm = wid >> 2, wn = wid & 3;
  const int m0 = blockIdx.x * 128, n0 = blockIdx.y * 128;

  // staging decomposition: 512 slots of 16B per matrix = 128 rows x 4 segs
  const int srow = tid >> 2, sseg = tid & 3;
  const int aoff = (m0 + srow) * DIN + sseg * 8;
  const int boff = (n0 + srow) * DIN + sseg * 8;
  const int lofs = (wid * 64) * 8;   // wave-uniform LDS base (ushorts)

  gl_lds16(&xb[aoff], &Sh[lofs]);
  gl_lds16(&w3[boff], &Sh[8192 + lofs]);

  f32x4 acc[4][2] = {};
  for (int t = 0; t < 32; ++t) {
    const int buf = t & 1;
    __syncthreads();
    if (t < 31) {
      int kt2 = (t + 1) * 32, b2 = buf ^ 1;
      gl_lds16(&xb[aoff + kt2], &Sh[b2 * 4096 + lofs]);
      gl_lds16(&w3[boff + kt2], &Sh[8192 + b2 * 4096 + lofs]);
    }
    const unsigned short* As = &Sh[buf * 4096];
    const unsigned short* Bs = &Sh[8192 + buf * 4096];
    short8 af[4], bf[2];
#pragma unroll
    for (int mt = 0; mt < 4; ++mt)
      af[mt] = *(const short8*)&As[(wm * 64 + mt * 16 + l16) * 32 + quad * 8];
#pragma unroll
    for (int nt = 0; nt < 2; ++nt)
      bf[nt] = *(const short8*)&Bs[(wn * 32 + nt * 16 + l16) * 32 + quad * 8];
#pragma unroll
    for (int mt = 0; mt < 4; ++mt)
#pragma unroll
      for (int nt = 0; nt < 2; ++nt)
        acc[mt][nt] = __builtin_amdgcn_mfma_f32_16x16x32_bf16(
            af[mt], bf[nt], acc[mt][nt], 0, 0, 0);
  }
  if (blockIdx.y >= 8) {
    // whole 128x128 tile is V: transpose via LDS, store coalesced to vT
    const int l = m0 >> 11, mloc = m0 & 2047;
#pragma unroll
    for (int chunk = 0; chunk < 2; ++chunk) {
      __syncthreads();
      if ((wn >> 1) == chunk) {
#pragma unroll
        for (int mt = 0; mt < 4; ++mt)
#pragma unroll
          for (int nt = 0; nt < 2; ++nt) {
            int col = (wn & 1) * 32 + nt * 16 + l16;   // 0..63 within chunk
            int rowb = wm * 64 + mt * 16 + quad * 4;
            ushort4 pv;
            pv.x = f2bf(acc[mt][nt][0]);
            pv.y = f2bf(acc[mt][nt][1]);
            pv.z = f2bf(acc[mt][nt][2]);
            pv.w = f2bf(acc[mt][nt][3]);
            *(ushort4*)&Sh[col * 136 + rowb] = pv;
          }
      }
      __syncthreads();
      int hh = ((n0 + chunk * 64) & 511) >> 6;
#pragma unroll
      for (int it = 0; it < 2; ++it) {
        int c = it * 512 + tid;
        int cl = c >> 4, seg = c & 15;  // d = cl, n-seg
        short8 vv = *(const short8*)&Sh[cl * 136 + seg * 8];
        *(short8*)&vtp[((size_t)((l * H_DIM + hh) * DH + cl)) * N_DIM + mloc +
                       seg * 8] = vv;
      }
    }
  } else {
    // Q/K tile: two 64-col head-chunks; stage [row][72] then b128 stores.
    const int l = m0 >> 11, nloc = m0 & 2047;
    const int hbase = (n0 & 511) >> 6;
    unsigned short* dstp = (n0 >> 9) ? kp : qp;
#pragma unroll
    for (int chunk = 0; chunk < 2; ++chunk) {
      __syncthreads();
      if ((wn >> 1) == chunk) {
#pragma unroll
        for (int mt = 0; mt < 4; ++mt)
#pragma unroll
          for (int nt = 0; nt < 2; ++nt) {
            int col = (wn & 1) * 32 + nt * 16 + l16;   // d within head
            int rowb = wm * 64 + mt * 16 + quad * 4;
#pragma unroll
            for (int r = 0; r < 4; ++r)
              Sh[(rowb + r) * 72 + col] = f2bf(acc[mt][nt][r]);
          }
      }
      __syncthreads();
      int hh = hbase + chunk;
      unsigned short* db =
          dstp + ((size_t)(l * H_DIM + hh) * N_DIM + nloc) * DH;
#pragma unroll
      for (int it = 0; it < 2; ++it) {
        int c = it * 512 + tid;       // 1024 slots = 128 rows x 8 segs
        int row = c >> 3, seg = c & 7;
        short8 vv = *(const short8*)&Sh[row * 72 + seg * 8];
        *(short8*)&db[row * DH + seg * 8] = vv;
      }
    }
  }
}

// ---------------------------------------------------------------- attention
// r12 structure (benched 64.9/64.6 us) + r14: s_setprio(1/0) around the QK
// and PV MFMA clusters. r12 runs 4 INDEPENDENT blocks/CU (no cross-block
// barriers) -- exactly the m191 regime where setprio measured +4-7% (vs the
// m190 lockstep-GEMM null). Everything else identical to r12.
#define PW_S 64
__launch_bounds__(256, 4)
__global__ void attn_kernel(const unsigned short* __restrict__ qg,
                            const unsigned short* __restrict__ kg,
                            const unsigned short* __restrict__ vtg,
                            const float* __restrict__ bias,
                            unsigned short* __restrict__ aout) {
  __shared__ __align__(16) unsigned short Ks[2][64 * 64];   // 2x8 KB
  __shared__ __align__(16) unsigned short Vs[2][64 * 64];   // 2x8 KB
  __shared__ __align__(16) unsigned short Pw[64 * PW_S];    // 8 KB
  const int tid = threadIdx.x, lane = tid & 63, wid = tid >> 6;  // wid 0..3
  const int l16 = lane & 15, quad = lane >> 4;
  // XCD swizzle: bid%8 = XCD (round-robin dispatch); 4 lh per XCD.
  const int bid = blockIdx.x;
  const int xcd = bid & 7, j = bid >> 3;      // j in 0..127
  const int lh = xcd * 4 + (j >> 5);          // 32 q-blocks per lh
  const int q0 = (j & 31) << 6;               // q-tiles of 64
  const int l = lh >> 3, h = lh & 7;
  const unsigned short* Qb = qg + (size_t)lh * N_DIM * DH;
  const unsigned short* Kb = kg + (size_t)lh * N_DIM * DH;
  const unsigned short* Vt = vtg + (size_t)lh * DH * N_DIM;
  const float* bl = bias + l * N_DIM;

  // Q B-frags: B[k=dh][n=qrow], lane l16 = qrow (wave owns 16 rows)
  short8 qf[2];
#pragma unroll
  for (int ks = 0; ks < 2; ++ks)
    qf[ks] = *(const short8*)&Qb[(q0 + wid * 16 + l16) * DH + ks * 32 +
                                 quad * 8];

  f32x4 o[4] = {};        // O C-layout: row quad*4+r=qrow, col nt*16+l16=d
  float lsum = 0.f;       // per-lane row-sum for qrow = l16

  // staging offsets (loop-invariant): 64 rows x 8 slots of 16B, slot
  // rotated by row; K and V tiles share the decomposition (64x64 bf16).
  // 512 granules / 256 threads = 2 per thread.
  int kof[2], ldsb[2];
  size_t vof[2];
#pragma unroll
  for (int it = 0; it < 2; ++it) {
    int c = it * 256 + tid;
    int rr = c >> 3, sl = c & 7, gs = (sl + rr) & 7;
    kof[it] = rr * DH + gs * 8;
    vof[it] = (size_t)rr * N_DIM + gs * 8;
    ldsb[it] = (it * 256 + wid * 64) * 8;   // wave-uniform LDS base
  }

  // stage tile 0 into buffer 0
#pragma unroll
  for (int it = 0; it < 2; ++it) {
    gl_lds16(&Kb[kof[it]], &Ks[0][ldsb[it]]);
    gl_lds16(&Vt[vof[it]], &Vs[0][ldsb[it]]);
  }

  for (int t = 0; t < 32; ++t) {
    const int kv = t << 6, buf = t & 1;
    __syncthreads();  // buf's DMA (issued last iter) landed; everyone done
                      // reading buf^1 from tile t-1
    if (t < 31) {     // issue tile t+1's DMA into the other buffer NOW
      int kv2 = kv + 64, b2 = buf ^ 1;
#pragma unroll
      for (int it = 0; it < 2; ++it) {
        gl_lds16(&Kb[(kv2 << 6) + kof[it]], &Ks[b2][ldsb[it]]);
        gl_lds16(&Vt[vof[it] + kv2], &Vs[b2][ldsb[it]]);
      }
    }
    const unsigned short* Kst = Ks[buf];
    const unsigned short* Vst = Vs[buf];

    // S^T = K Q : m=key (4 tiles of 16), n=qrow (16 rows per wave)
    f32x4 sc[4] = {};
    __builtin_amdgcn_s_setprio(1);
#pragma unroll
    for (int nt = 0; nt < 4; ++nt)
#pragma unroll
      for (int ks = 0; ks < 2; ++ks) {
        int s = (ks * 4 + quad - l16) & 7;
        short8 kf = *(const short8*)&Kst[(nt * 16 + l16) * 64 + s * 8];
        sc[nt] = __builtin_amdgcn_mfma_f32_16x16x32_bf16(kf, qf[ks], sc[nt],
                                                         0, 0, 0);
      }
    __builtin_amdgcn_s_setprio(0);
    // softmax + pack + stash (wave-private rows, granule rot by l16)
    unsigned short* pr = &Pw[(wid * 16 + l16) * PW_S];
#pragma unroll
    for (int nt = 0; nt < 4; ++nt) {
      float4 b4 = *(const float4*)&bl[kv + nt * 16 + quad * 4];
      // exp(s*0.125 + b) == exp2(s*(0.125*log2e) + b'); b in {0,-1e30}
      float p0 = fexp2(fmaf(sc[nt][0], 0.18033688011f, b4.x));
      float p1 = fexp2(fmaf(sc[nt][1], 0.18033688011f, b4.y));
      float p2 = fexp2(fmaf(sc[nt][2], 0.18033688011f, b4.z));
      float p3 = fexp2(fmaf(sc[nt][3], 0.18033688011f, b4.w));
      lsum += (p0 + p1) + (p2 + p3);
      uint2 pkv = make_uint2(cvtpk(p0, p1), cvtpk(p2, p3));
      int gk = nt * 2 + (quad >> 1);          // 8-key granule in tile
      int s = (gk + l16) & 7;
      *(uint2*)&pr[s * 8 + (quad & 1) * 4] = pkv;
    }
    // O += P V over this tile's 64 keys (2 chunks of 32)
    __builtin_amdgcn_s_setprio(1);
#pragma unroll
    for (int g = 0; g < 2; ++g) {
      int sp = (g * 4 + quad + l16) & 7;
      short8 pa = *(const short8*)&Pw[(wid * 16 + l16) * PW_S + sp * 8];
#pragma unroll
      for (int nt = 0; nt < 4; ++nt) {
        int dd = nt * 16 + l16;
        int sv2 = (g * 4 + quad - l16) & 7;
        short8 vb = *(const short8*)&Vst[dd * 64 + sv2 * 8];
        o[nt] = __builtin_amdgcn_mfma_f32_16x16x32_bf16(pa, vb, o[nt],
                                                        0, 0, 0);
      }
    }
    __builtin_amdgcn_s_setprio(0);
  }
  // row-sums: reduce across the 4 quads holding the same qrow=l16
  lsum += __shfl_xor(lsum, 16);
  lsum += __shfl_xor(lsum, 32);
#pragma unroll
  for (int r = 0; r < 4; ++r) {
    float inv = 1.f / __shfl(lsum, quad * 4 + r);
    int row = q0 + wid * 16 + quad * 4 + r;
#pragma unroll
    for (int nt = 0; nt < 4; ++nt)
      aout[(size_t)(l * N_DIM + row) * INNER + h * DH + nt * 16 + l16] =
          f2bf(o[nt][r] * inv);
  }
}

// ---------------------------------------------------------------- out GEMM
// out[8192][1024] = attn[8192][512] @ Wo^T + bo (fp32 out). 128x64 tiles,
// 4 blocks/CU, dbuf one-barrier.
__launch_bounds__(256, 4)
__global__ void gemm_out(const unsigned short* __restrict__ a,
                         const unsigned short* __restrict__ wo,
                         const float* __restrict__ bo,
                         float* __restrict__ out) {
  __shared__ __align__(16) unsigned short Sh[12288];  // A dbuf(8K) | B dbuf(4K)
  const int tid = threadIdx.x, lane = tid & 63, wid = tid >> 6;
  const int l16 = lane & 15, quad = lane >> 4;
  const int wm = wid >> 1, wn = wid & 1;
  const int m0 = blockIdx.x * 128, n0 = blockIdx.y * 64;

  int aoff[2], lofsA[2];
#pragma unroll
  for (int it = 0; it < 2; ++it) {
    int c = it * 256 + wid * 64 + lane;
    int row = c >> 2, kseg = c & 3;
    aoff[it] = (m0 + row) * INNER + kseg * 8;
    lofsA[it] = (it * 256 + wid * 64) * 8;
  }
  int boff, lofsB;
  {
    int c = wid * 64 + lane;
    int row = c >> 2, kseg = c & 3;
    boff = (n0 + row) * INNER + kseg * 8;
    lofsB = (wid * 64) * 8;
  }

#pragma unroll
  for (int it = 0; it < 2; ++it)
    gl_lds16(&a[aoff[it]], &Sh[lofsA[it]]);
  gl_lds16(&wo[boff], &Sh[8192 + lofsB]);

  f32x4 acc[4][2] = {};
  for (int t = 0; t < 16; ++t) {
    const int buf = t & 1;
    __syncthreads();
    if (t < 15) {
      int kt2 = (t + 1) * 32, b2 = buf ^ 1;
#pragma unroll
      for (int it = 0; it < 2; ++it)
        gl_lds16(&a[aoff[it] + kt2], &Sh[b2 * 4096 + lofsA[it]]);
      gl_lds16(&wo[boff + kt2], &Sh[8192 + b2 * 2048 + lofsB]);
    }
    const unsigned short* As = &Sh[buf * 4096];
    const unsigned short* Bs = &Sh[8192 + buf * 2048];
    short8 af[4], bf[2];
#pragma unroll
    for (int mt = 0; mt < 4; ++mt)
      af[mt] = *(const short8*)&As[(wm * 64 + mt * 16 + l16) * 32 + quad * 8];
#pragma unroll
    for (int nt = 0; nt < 2; ++nt)
      bf[nt] = *(const short8*)&Bs[(wn * 32 + nt * 16 + l16) * 32 + quad * 8];
#pragma unroll
    for (int mt = 0; mt < 4; ++mt)
#pragma unroll
      for (int nt = 0; nt < 2; ++nt)
        acc[mt][nt] = __builtin_amdgcn_mfma_f32_16x16x32_bf16(
            af[mt], bf[nt], acc[mt][nt], 0, 0, 0);
  }
#pragma unroll
  for (int mt = 0; mt < 4; ++mt)
#pragma unroll
    for (int nt = 0; nt < 2; ++nt)
#pragma unroll
      for (int r = 0; r < 4; ++r) {
        int grow = m0 + wm * 64 + mt * 16 + quad * 4 + r;
        int gcol = n0 + wn * 32 + nt * 16 + l16;
        out[(size_t)grow * DIN + gcol] = acc[mt][nt][r] + bo[gcol];
      }
}

// ---------------------------------------------------------------- launch
extern "C" void kernel_launch(void* const* d_in, const int* in_sizes, int n_in,
                              void* d_out, int out_size, void* d_ws,
                              size_t ws_size, hipStream_t stream) {
  const float* x  = (const float*)d_in[0];
  const float* Wq = (const float*)d_in[1];
  const float* Wk = (const float*)d_in[2];
  const float* Wv = (const float*)d_in[3];
  const float* Wo = (const float*)d_in[4];
  const float* bo = (const float*)d_in[5];
  const unsigned char* mask = (const unsigned char*)d_in[6];
  float* out = (float*)d_out;

  char* ws = (char*)d_ws;
  unsigned short* xb  = (unsigned short*)(ws + 0);         // 16 MB
  unsigned short* w3  = (unsigned short*)(ws + 16777216);  // 3 MB
  unsigned short* wob = (unsigned short*)(ws + 19922944);  // 1 MB
  unsigned short* q   = (unsigned short*)(ws + 20971520);  // 8 MB
  unsigned short* k   = (unsigned short*)(ws + 29360128);  // 8 MB
  unsigned short* vt  = (unsigned short*)(ws + 37748736);  // 8 MB (transposed)
  unsigned short* att = (unsigned short*)(ws + 46137344);  // 8 MB
  float* bias         = (float*)(ws + 54525952);           // 32 KB

  cast_all<<<10241, 256, 0, stream>>>(x, Wq, Wk, Wv, Wo, xb, w3, wob, mask,
                                      bias);
  gemm_qkv<<<dim3(64, 12), 512, 0, stream>>>(xb, w3, q, k, vt);
  // r14 DIAGNOSTIC: duplicate launch. Writes identical outputs; the total
  // delta vs the single-launch baseline (209.5us, corrected by the attn
  // setprio gain) measures qkv's warm duration directly.
  gemm_qkv<<<dim3(64, 12), 512, 0, stream>>>(xb, w3, q, k, vt);
  attn_kernel<<<1024, 256, 0, stream>>>(q, k, vt, bias, att);
  gemm_out<<<dim3(64, 16), 256, 0, stream>>>(att, wob, bo, out);
}

// Round 13
// 209.429 us; speedup vs baseline: 1.1682x; 1.1682x over previous
//
#include <hip/hip_runtime.h>
#include <hip/hip_bf16.h>

// Shapes (fixed by the reference)
#define L_DIM 4
#define N_DIM 2048
#define DIN   1024
#define H_DIM 8
#define DH    64
#define INNER 512   // H*DH

typedef __attribute__((ext_vector_type(8))) short short8;
typedef __attribute__((ext_vector_type(4))) float f32x4;

__device__ __forceinline__ unsigned short f2bf(float f) {
  unsigned u = __builtin_bit_cast(unsigned, f);
  u += 0x7fffu + ((u >> 16) & 1u);   // RNE
  return (unsigned short)(u >> 16);
}

// single-instruction 2xf32 -> packed bf16x2 (RNE); low16 = a, high16 = b
__device__ __forceinline__ unsigned cvtpk(float a, float b) {
  unsigned r;
  asm("v_cvt_pk_bf16_f32 %0, %1, %2" : "=v"(r) : "v"(a), "v"(b));
  return r;
}

// v_exp_f32 computes 2^x; log2e pre-folded into the softmax scale.
__device__ __forceinline__ float fexp2(float x) {
  float r;
  asm("v_exp_f32 %0, %1" : "=v"(r) : "v"(x));
  return r;
}

// async global->LDS, 16B per lane; lds base must be wave-uniform
typedef __attribute__((address_space(3))) unsigned int lds_uint;
typedef const __attribute__((address_space(1))) unsigned int glob_uint;
__device__ __forceinline__ void gl_lds16(const unsigned short* g,
                                         unsigned short* l) {
  __builtin_amdgcn_global_load_lds((glob_uint*)g, (lds_uint*)l, 16, 0, 0);
}

// ------------------------------------------------- fused casts + mask bias
__global__ void cast_all(const float* __restrict__ x,
                         const float* __restrict__ wq,
                         const float* __restrict__ wk,
                         const float* __restrict__ wv,
                         const float* __restrict__ wo,
                         unsigned short* __restrict__ xb,
                         unsigned short* __restrict__ w3,
                         unsigned short* __restrict__ wob,
                         const unsigned char* __restrict__ mraw,
                         float* __restrict__ bias) {
  __shared__ int votes[2];
  int bid = blockIdx.x, t = threadIdx.x;
  if (bid == 10240) {
    // mask -> additive bias (0 valid, -1e30 masked); dtype sniffed.
    if (t < 2) votes[t] = 0;
    __syncthreads();
    const unsigned int* m32 = (const unsigned int*)mraw;
    int anyf = 0, any8 = 0;
    for (int i = t; i < 2048; i += 256) {
      unsigned w = m32[i];
      if (w == 0x3f800000u) anyf = 1;
      if (w & 0xffffff00u) any8 = 1;
    }
    if (anyf) atomicOr(&votes[0], 1);
    if (any8) atomicOr(&votes[1], 1);
    __syncthreads();
    int fmt = votes[0] ? 2 : (votes[1] ? 1 : 0);
    for (int i = t; i < L_DIM * N_DIM; i += 256) {
      int mv;
      if (fmt == 2)      mv = ((const float*)mraw)[i] != 0.0f;
      else if (fmt == 1) mv = mraw[i] != 0;
      else               mv = ((const int*)mraw)[i] != 0;
      bias[i] = mv ? 0.0f : -1e30f;
    }
    return;
  }
  int i = (bid * 256 + t) * 4;
  const float* src; unsigned short* dst; int off;
  if (i < 8388608)      { src = x;  dst = xb;           off = i; }
  else if (i < 8912896) { src = wq; dst = w3;           off = i - 8388608; }
  else if (i < 9437184) { src = wk; dst = w3 + 524288;  off = i - 8912896; }
  else if (i < 9961472) { src = wv; dst = w3 + 1048576; off = i - 9437184; }
  else                  { src = wo; dst = wob;          off = i - 9961472; }
  float4 f = *(const float4*)(src + off);
  ushort4 o4;
  o4.x = f2bf(f.x); o4.y = f2bf(f.y); o4.z = f2bf(f.z); o4.w = f2bf(f.w);
  *(ushort4*)(dst + off) = o4;
}

// ---------------------------------------------------------------- QKV GEMM
// C[8192][1536] = Xb[8192][1024] @ W3^T. r13 structure (512 thr / 8 waves,
// 128x128/BK=32 dbuf-one-barrier, 32KB LDS, 3 blocks/CU; measured 36.8us).
// r16 (3rd submit; grid flattened to 1-D to drop the x/y linearization
// assumption): XCD-aware block swizzle. Unswizzled, same-A-panel blocks
// scatter across the 8 non-coherent L2s -> ~384MB of staging reads hit L3
// (10.4 TB/s demand at 36.8us = plausibly L3-BW-bound). Remap so XCD x
// owns bx in [8x,8x+8): co-resident same-panel blocks become L2-local.
// Pure bijective index permutation, zero schedule change.
__launch_bounds__(512, 6)
__global__ void gemm_qkv(const unsigned short* __restrict__ xb,
                         const unsigned short* __restrict__ w3,
                         unsigned short* __restrict__ qp,
                         unsigned short* __restrict__ kp,
                         unsigned short* __restrict__ vtp) {
  __shared__ __align__(16) unsigned short Sh[16384];  // A dbuf | B dbuf
  const int tid = threadIdx.x, lane = tid & 63, wid = tid >> 6;  // 0..7
  const int l16 = lane & 15, quad = lane >> 4;
  const int wm = wid >> 2, wn = wid & 3;
  // 1-D grid of 768; hardware dispatches blockIdx.x round-robin over XCDs.
  const int lin = blockIdx.x;
  const int xcd = lin & 7, slot = lin >> 3;      // slot 0..95
  const int bx = xcd * 8 + (slot & 7);           // 0..63
  const int by = slot >> 3;                      // 0..11
  const int m0 = bx * 128, n0 = by * 128;

  // staging decomposition: 512 slots of 16B per matrix = 128 rows x 4 segs
  const int srow = tid >> 2, sseg = tid & 3;
  const int aoff = (m0 + srow) * DIN + sseg * 8;
  const int boff = (n0 + srow) * DIN + sseg * 8;
  const int lofs = (wid * 64) * 8;   // wave-uniform LDS base (ushorts)

  gl_lds16(&xb[aoff], &Sh[lofs]);
  gl_lds16(&w3[boff], &Sh[8192 + lofs]);

  f32x4 acc[4][2] = {};
  for (int t = 0; t < 32; ++t) {
    const int buf = t & 1;
    __syncthreads();
    if (t < 31) {
      int kt2 = (t + 1) * 32, b2 = buf ^ 1;
      gl_lds16(&xb[aoff + kt2], &Sh[b2 * 4096 + lofs]);
      gl_lds16(&w3[boff + kt2], &Sh[8192 + b2 * 4096 + lofs]);
    }
    const unsigned short* As = &Sh[buf * 4096];
    const unsigned short* Bs = &Sh[8192 + buf * 4096];
    short8 af[4], bf[2];
#pragma unroll
    for (int mt = 0; mt < 4; ++mt)
      af[mt] = *(const short8*)&As[(wm * 64 + mt * 16 + l16) * 32 + quad * 8];
#pragma unroll
    for (int nt = 0; nt < 2; ++nt)
      bf[nt] = *(const short8*)&Bs[(wn * 32 + nt * 16 + l16) * 32 + quad * 8];
#pragma unroll
    for (int mt = 0; mt < 4; ++mt)
#pragma unroll
      for (int nt = 0; nt < 2; ++nt)
        acc[mt][nt] = __builtin_amdgcn_mfma_f32_16x16x32_bf16(
            af[mt], bf[nt], acc[mt][nt], 0, 0, 0);
  }
  if (by >= 8) {
    // whole 128x128 tile is V: transpose via LDS, store coalesced to vT
    const int l = m0 >> 11, mloc = m0 & 2047;
#pragma unroll
    for (int chunk = 0; chunk < 2; ++chunk) {
      __syncthreads();
      if ((wn >> 1) == chunk) {
#pragma unroll
        for (int mt = 0; mt < 4; ++mt)
#pragma unroll
          for (int nt = 0; nt < 2; ++nt) {
            int col = (wn & 1) * 32 + nt * 16 + l16;   // 0..63 within chunk
            int rowb = wm * 64 + mt * 16 + quad * 4;
            ushort4 pv;
            pv.x = f2bf(acc[mt][nt][0]);
            pv.y = f2bf(acc[mt][nt][1]);
            pv.z = f2bf(acc[mt][nt][2]);
            pv.w = f2bf(acc[mt][nt][3]);
            *(ushort4*)&Sh[col * 136 + rowb] = pv;
          }
      }
      __syncthreads();
      int hh = ((n0 + chunk * 64) & 511) >> 6;
#pragma unroll
      for (int it = 0; it < 2; ++it) {
        int c = it * 512 + tid;
        int cl = c >> 4, seg = c & 15;  // d = cl, n-seg
        short8 vv = *(const short8*)&Sh[cl * 136 + seg * 8];
        *(short8*)&vtp[((size_t)((l * H_DIM + hh) * DH + cl)) * N_DIM + mloc +
                       seg * 8] = vv;
      }
    }
  } else {
    // Q/K tile: two 64-col head-chunks; stage [row][72] then b128 stores.
    const int l = m0 >> 11, nloc = m0 & 2047;
    const int hbase = (n0 & 511) >> 6;
    unsigned short* dstp = (n0 >> 9) ? kp : qp;
#pragma unroll
    for (int chunk = 0; chunk < 2; ++chunk) {
      __syncthreads();
      if ((wn >> 1) == chunk) {
#pragma unroll
        for (int mt = 0; mt < 4; ++mt)
#pragma unroll
          for (int nt = 0; nt < 2; ++nt) {
            int col = (wn & 1) * 32 + nt * 16 + l16;   // d within head
            int rowb = wm * 64 + mt * 16 + quad * 4;
#pragma unroll
            for (int r = 0; r < 4; ++r)
              Sh[(rowb + r) * 72 + col] = f2bf(acc[mt][nt][r]);
          }
      }
      __syncthreads();
      int hh = hbase + chunk;
      unsigned short* db =
          dstp + ((size_t)(l * H_DIM + hh) * N_DIM + nloc) * DH;
#pragma unroll
      for (int it = 0; it < 2; ++it) {
        int c = it * 512 + tid;       // 1024 slots = 128 rows x 8 segs
        int row = c >> 3, seg = c & 7;
        short8 vv = *(const short8*)&Sh[row * 72 + seg * 8];
        *(short8*)&db[row * DH + seg * 8] = vv;
      }
    }
  }
}

// ---------------------------------------------------------------- attention
// r12 structure + setprio (benched 63.0 us): QB=64, KVBLK=64, 256 threads =
// 4 waves x 16 rows, r8 LDS layouts, dbuf one-barrier DMA, 40KB LDS ->
// 4 independent blocks/CU (m191 setprio regime: measured -1.6us here).
#define PW_S 64
__launch_bounds__(256, 4)
__global__ void attn_kernel(const unsigned short* __restrict__ qg,
                            const unsigned short* __restrict__ kg,
                            const unsigned short* __restrict__ vtg,
                            const float* __restrict__ bias,
                            unsigned short* __restrict__ aout) {
  __shared__ __align__(16) unsigned short Ks[2][64 * 64];   // 2x8 KB
  __shared__ __align__(16) unsigned short Vs[2][64 * 64];   // 2x8 KB
  __shared__ __align__(16) unsigned short Pw[64 * PW_S];    // 8 KB
  const int tid = threadIdx.x, lane = tid & 63, wid = tid >> 6;  // wid 0..3
  const int l16 = lane & 15, quad = lane >> 4;
  // XCD swizzle: bid%8 = XCD (round-robin dispatch); 4 lh per XCD.
  const int bid = blockIdx.x;
  const int xcd = bid & 7, j = bid >> 3;      // j in 0..127
  const int lh = xcd * 4 + (j >> 5);          // 32 q-blocks per lh
  const int q0 = (j & 31) << 6;               // q-tiles of 64
  const int l = lh >> 3, h = lh & 7;
  const unsigned short* Qb = qg + (size_t)lh * N_DIM * DH;
  const unsigned short* Kb = kg + (size_t)lh * N_DIM * DH;
  const unsigned short* Vt = vtg + (size_t)lh * DH * N_DIM;
  const float* bl = bias + l * N_DIM;

  // Q B-frags: B[k=dh][n=qrow], lane l16 = qrow (wave owns 16 rows)
  short8 qf[2];
#pragma unroll
  for (int ks = 0; ks < 2; ++ks)
    qf[ks] = *(const short8*)&Qb[(q0 + wid * 16 + l16) * DH + ks * 32 +
                                 quad * 8];

  f32x4 o[4] = {};        // O C-layout: row quad*4+r=qrow, col nt*16+l16=d
  float lsum = 0.f;       // per-lane row-sum for qrow = l16

  // staging offsets (loop-invariant): 64 rows x 8 slots of 16B, slot
  // rotated by row; K and V tiles share the decomposition (64x64 bf16).
  // 512 granules / 256 threads = 2 per thread.
  int kof[2], ldsb[2];
  size_t vof[2];
#pragma unroll
  for (int it = 0; it < 2; ++it) {
    int c = it * 256 + tid;
    int rr = c >> 3, sl = c & 7, gs = (sl + rr) & 7;
    kof[it] = rr * DH + gs * 8;
    vof[it] = (size_t)rr * N_DIM + gs * 8;
    ldsb[it] = (it * 256 + wid * 64) * 8;   // wave-uniform LDS base
  }

  // stage tile 0 into buffer 0
#pragma unroll
  for (int it = 0; it < 2; ++it) {
    gl_lds16(&Kb[kof[it]], &Ks[0][ldsb[it]]);
    gl_lds16(&Vt[vof[it]], &Vs[0][ldsb[it]]);
  }

  for (int t = 0; t < 32; ++t) {
    const int kv = t << 6, buf = t & 1;
    __syncthreads();  // buf's DMA (issued last iter) landed; everyone done
                      // reading buf^1 from tile t-1
    if (t < 31) {     // issue tile t+1's DMA into the other buffer NOW
      int kv2 = kv + 64, b2 = buf ^ 1;
#pragma unroll
      for (int it = 0; it < 2; ++it) {
        gl_lds16(&Kb[(kv2 << 6) + kof[it]], &Ks[b2][ldsb[it]]);
        gl_lds16(&Vt[vof[it] + kv2], &Vs[b2][ldsb[it]]);
      }
    }
    const unsigned short* Kst = Ks[buf];
    const unsigned short* Vst = Vs[buf];

    // S^T = K Q : m=key (4 tiles of 16), n=qrow (16 rows per wave)
    f32x4 sc[4] = {};
    __builtin_amdgcn_s_setprio(1);
#pragma unroll
    for (int nt = 0; nt < 4; ++nt)
#pragma unroll
      for (int ks = 0; ks < 2; ++ks) {
        int s = (ks * 4 + quad - l16) & 7;
        short8 kf = *(const short8*)&Kst[(nt * 16 + l16) * 64 + s * 8];
        sc[nt] = __builtin_amdgcn_mfma_f32_16x16x32_bf16(kf, qf[ks], sc[nt],
                                                         0, 0, 0);
      }
    __builtin_amdgcn_s_setprio(0);
    // softmax + pack + stash (wave-private rows, granule rot by l16)
    unsigned short* pr = &Pw[(wid * 16 + l16) * PW_S];
#pragma unroll
    for (int nt = 0; nt < 4; ++nt) {
      float4 b4 = *(const float4*)&bl[kv + nt * 16 + quad * 4];
      // exp(s*0.125 + b) == exp2(s*(0.125*log2e) + b'); b in {0,-1e30}
      float p0 = fexp2(fmaf(sc[nt][0], 0.18033688011f, b4.x));
      float p1 = fexp2(fmaf(sc[nt][1], 0.18033688011f, b4.y));
      float p2 = fexp2(fmaf(sc[nt][2], 0.18033688011f, b4.z));
      float p3 = fexp2(fmaf(sc[nt][3], 0.18033688011f, b4.w));
      lsum += (p0 + p1) + (p2 + p3);
      uint2 pkv = make_uint2(cvtpk(p0, p1), cvtpk(p2, p3));
      int gk = nt * 2 + (quad >> 1);          // 8-key granule in tile
      int s = (gk + l16) & 7;
      *(uint2*)&pr[s * 8 + (quad & 1) * 4] = pkv;
    }
    // O += P V over this tile's 64 keys (2 chunks of 32)
    __builtin_amdgcn_s_setprio(1);
#pragma unroll
    for (int g = 0; g < 2; ++g) {
      int sp = (g * 4 + quad + l16) & 7;
      short8 pa = *(const short8*)&Pw[(wid * 16 + l16) * PW_S + sp * 8];
#pragma unroll
      for (int nt = 0; nt < 4; ++nt) {
        int dd = nt * 16 + l16;
        int sv2 = (g * 4 + quad - l16) & 7;
        short8 vb = *(const short8*)&Vst[dd * 64 + sv2 * 8];
        o[nt] = __builtin_amdgcn_mfma_f32_16x16x32_bf16(pa, vb, o[nt],
                                                        0, 0, 0);
      }
    }
    __builtin_amdgcn_s_setprio(0);
  }
  // row-sums: reduce across the 4 quads holding the same qrow=l16
  lsum += __shfl_xor(lsum, 16);
  lsum += __shfl_xor(lsum, 32);
#pragma unroll
  for (int r = 0; r < 4; ++r) {
    float inv = 1.f / __shfl(lsum, quad * 4 + r);
    int row = q0 + wid * 16 + quad * 4 + r;
#pragma unroll
    for (int nt = 0; nt < 4; ++nt)
      aout[(size_t)(l * N_DIM + row) * INNER + h * DH + nt * 16 + l16] =
          f2bf(o[nt][r] * inv);
  }
}

// ---------------------------------------------------------------- out GEMM
// out[8192][1024] = attn[8192][512] @ Wo^T + bo (fp32 out). 128x64 tiles,
// 4 blocks/CU, dbuf one-barrier. r16: XCD swizzle, 1-D grid of 1024
// (per-XCD working set A 1MB + B 1MB -> fully L2-resident).
__launch_bounds__(256, 4)
__global__ void gemm_out(const unsigned short* __restrict__ a,
                         const unsigned short* __restrict__ wo,
                         const float* __restrict__ bo,
                         float* __restrict__ out) {
  __shared__ __align__(16) unsigned short Sh[12288];  // A dbuf(8K) | B dbuf(4K)
  const int tid = threadIdx.x, lane = tid & 63, wid = tid >> 6;
  const int l16 = lane & 15, quad = lane >> 4;
  const int wm = wid >> 1, wn = wid & 1;
  const int lin = blockIdx.x;                    // 1-D grid of 1024
  const int xcd = lin & 7, slot = lin >> 3;      // slot 0..127
  const int bx = xcd * 8 + (slot & 7);           // 0..63
  const int by = slot >> 3;                      // 0..15
  const int m0 = bx * 128, n0 = by * 64;

  int aoff[2], lofsA[2];
#pragma unroll
  for (int it = 0; it < 2; ++it) {
    int c = it * 256 + wid * 64 + lane;
    int row = c >> 2, kseg = c & 3;
    aoff[it] = (m0 + row) * INNER + kseg * 8;
    lofsA[it] = (it * 256 + wid * 64) * 8;
  }
  int boff, lofsB;
  {
    int c = wid * 64 + lane;
    int row = c >> 2, kseg = c & 3;
    boff = (n0 + row) * INNER + kseg * 8;
    lofsB = (wid * 64) * 8;
  }

#pragma unroll
  for (int it = 0; it < 2; ++it)
    gl_lds16(&a[aoff[it]], &Sh[lofsA[it]]);
  gl_lds16(&wo[boff], &Sh[8192 + lofsB]);

  f32x4 acc[4][2] = {};
  for (int t = 0; t < 16; ++t) {
    const int buf = t & 1;
    __syncthreads();
    if (t < 15) {
      int kt2 = (t + 1) * 32, b2 = buf ^ 1;
#pragma unroll
      for (int it = 0; it < 2; ++it)
        gl_lds16(&a[aoff[it] + kt2], &Sh[b2 * 4096 + lofsA[it]]);
      gl_lds16(&wo[boff + kt2], &Sh[8192 + b2 * 2048 + lofsB]);
    }
    const unsigned short* As = &Sh[buf * 4096];
    const unsigned short* Bs = &Sh[8192 + buf * 2048];
    short8 af[4], bf[2];
#pragma unroll
    for (int mt = 0; mt < 4; ++mt)
      af[mt] = *(const short8*)&As[(wm * 64 + mt * 16 + l16) * 32 + quad * 8];
#pragma unroll
    for (int nt = 0; nt < 2; ++nt)
      bf[nt] = *(const short8*)&Bs[(wn * 32 + nt * 16 + l16) * 32 + quad * 8];
#pragma unroll
    for (int mt = 0; mt < 4; ++mt)
#pragma unroll
      for (int nt = 0; nt < 2; ++nt)
        acc[mt][nt] = __builtin_amdgcn_mfma_f32_16x16x32_bf16(
            af[mt], bf[nt], acc[mt][nt], 0, 0, 0);
  }
#pragma unroll
  for (int mt = 0; mt < 4; ++mt)
#pragma unroll
    for (int nt = 0; nt < 2; ++nt)
#pragma unroll
      for (int r = 0; r < 4; ++r) {
        int grow = m0 + wm * 64 + mt * 16 + quad * 4 + r;
        int gcol = n0 + wn * 32 + nt * 16 + l16;
        out[(size_t)grow * DIN + gcol] = acc[mt][nt][r] + bo[gcol];
      }
}

// ---------------------------------------------------------------- launch
extern "C" void kernel_launch(void* const* d_in, const int* in_sizes, int n_in,
                              void* d_out, int out_size, void* d_ws,
                              size_t ws_size, hipStream_t stream) {
  const float* x  = (const float*)d_in[0];
  const float* Wq = (const float*)d_in[1];
  const float* Wk = (const float*)d_in[2];
  const float* Wv = (const float*)d_in[3];
  const float* Wo = (const float*)d_in[4];
  const float* bo = (const float*)d_in[5];
  const unsigned char* mask = (const unsigned char*)d_in[6];
  float* out = (float*)d_out;

  char* ws = (char*)d_ws;
  unsigned short* xb  = (unsigned short*)(ws + 0);         // 16 MB
  unsigned short* w3  = (unsigned short*)(ws + 16777216);  // 3 MB
  unsigned short* wob = (unsigned short*)(ws + 19922944);  // 1 MB
  unsigned short* q   = (unsigned short*)(ws + 20971520);  // 8 MB
  unsigned short* k   = (unsigned short*)(ws + 29360128);  // 8 MB
  unsigned short* vt  = (unsigned short*)(ws + 37748736);  // 8 MB (transposed)
  unsigned short* att = (unsigned short*)(ws + 46137344);  // 8 MB
  float* bias         = (float*)(ws + 54525952);           // 32 KB

  cast_all<<<10241, 256, 0, stream>>>(x, Wq, Wk, Wv, Wo, xb, w3, wob, mask,
                                      bias);
  gemm_qkv<<<768, 512, 0, stream>>>(xb, w3, q, k, vt);
  attn_kernel<<<1024, 256, 0, stream>>>(q, k, vt, bias, att);
  gemm_out<<<1024, 256, 0, stream>>>(att, wob, bo, out);
}